// Round 1
// baseline (454.530 us; speedup 1.0000x reference)
//
#include <hip/hip_runtime.h>
#include <hip/hip_bf16.h>

using bf16 = __hip_bfloat16;
using s8v  = __attribute__((ext_vector_type(8))) short;
using f4v  = __attribute__((ext_vector_type(4))) float;

constexpr int B_   = 4;
constexpr int P_   = 1024;
constexpr int KNB  = 32;
constexpr int D_   = 768;
constexpr int H_   = 12;
constexpr int S_   = P_ + 1;    // 1025
constexpr int M_   = B_ * S_;   // 4100
constexpr int MPAD = 4224;      // 33 * 128

#define DEVI static __device__ __forceinline__

DEVI float b2f_lo(unsigned u) { return __builtin_bit_cast(float, u << 16); }
DEVI float b2f_hi(unsigned u) { return __builtin_bit_cast(float, u & 0xffff0000u); }

// ---------------- weight fp32 (K x N) -> bf16 transposed (N x K) ----------------
template<int KK, int NN>
__global__ __launch_bounds__(256)
void wt_conv(const float* __restrict__ W, bf16* __restrict__ Wt) {
  __shared__ float t[32][33];
  int bk = blockIdx.x * 32, bn = blockIdx.y * 32;
  int tx = threadIdx.x & 31, ty = threadIdx.x >> 5;  // ty in 0..7
#pragma unroll
  for (int i = 0; i < 32; i += 8)
    t[ty + i][tx] = W[(size_t)(bk + ty + i) * NN + bn + tx];
  __syncthreads();
#pragma unroll
  for (int i = 0; i < 32; i += 8)
    Wt[(size_t)(bn + ty + i) * KK + bk + tx] = __float2bfloat16(t[tx][ty + i]);
}

// ---------------- LayerNorm fp32 -> bf16 (row = 768) ----------------
__global__ __launch_bounds__(256)
void ln_kernel(const float* __restrict__ x, const float* __restrict__ w,
               const float* __restrict__ b, bf16* __restrict__ out) {
  int row = blockIdx.x;
  const float* xr = x + (size_t)row * D_;
  int t = threadIdx.x;
  float v0 = xr[t], v1 = xr[t + 256], v2 = xr[t + 512];
  float s = v0 + v1 + v2;
  float ss = v0 * v0 + v1 * v1 + v2 * v2;
#pragma unroll
  for (int o = 32; o; o >>= 1) { s += __shfl_xor(s, o); ss += __shfl_xor(ss, o); }
  __shared__ float sm[4], sv[4];
  if ((t & 63) == 0) { sm[t >> 6] = s; sv[t >> 6] = ss; }
  __syncthreads();
  float S = sm[0] + sm[1] + sm[2] + sm[3];
  float SS = sv[0] + sv[1] + sv[2] + sv[3];
  float mean = S * (1.f / D_);
  float var  = SS * (1.f / D_) - mean * mean;
  float inv  = rsqrtf(var + 1e-5f);
  bf16* orow = out + (size_t)row * D_;
  orow[t]       = __float2bfloat16((v0 - mean) * inv * w[t]       + b[t]);
  orow[t + 256] = __float2bfloat16((v1 - mean) * inv * w[t + 256] + b[t + 256]);
  orow[t + 512] = __float2bfloat16((v2 - mean) * inv * w[t + 512] + b[t + 512]);
}

// ---------------- bf16 GEMM: C = A(MPADxK) * Bt(NxK)^T, fused epilogues ----------------
// MODE 0: + bias -> scatter to QKV buffer [3][B][H][S][64] bf16
// MODE 1: + bias + resid(fp32) -> fp32 dst [M][N]
// MODE 2: + bias -> gelu(exact) -> bf16 dst [MPAD][N]
template<int N, int K, int MODE>
__global__ __launch_bounds__(256)
void gemm_bf16(const bf16* __restrict__ A, const bf16* __restrict__ Bt,
               const float* __restrict__ bias, const float* __restrict__ resid,
               void* __restrict__ dst) {
  __shared__ bf16 lds[2][2][128 * 32];
  const int tm = blockIdx.x, tn = blockIdx.y;
  const int tid = threadIdx.x;
  const int wid = tid >> 6, lane = tid & 63;
  const int wr = wid >> 1, wc = wid & 1;

  auto stage = [&](int bufi, int step) {
    const int k0 = step * 32;
#pragma unroll
    for (int i = 0; i < 2; ++i) {
      int c = wid * 64 + i * 256 + lane;
      int r = c >> 2, slot = c & 3;
      int gs = slot ^ ((r >> 1) & 3);  // inverse-swizzled global source (rule 21)
      const bf16* ga = A + (size_t)(tm * 128 + r) * K + k0 + gs * 8;
      bf16* la = &lds[bufi][0][(wid * 64 + i * 256) * 8];
      __builtin_amdgcn_global_load_lds(
          (__attribute__((address_space(1))) void*)ga,
          (__attribute__((address_space(3))) void*)la, 16, 0, 0);
    }
#pragma unroll
    for (int i = 0; i < 2; ++i) {
      int c = wid * 64 + i * 256 + lane;
      int r = c >> 2, slot = c & 3;
      int gs = slot ^ ((r >> 1) & 3);
      const bf16* ga = Bt + (size_t)(tn * 128 + r) * K + k0 + gs * 8;
      bf16* la = &lds[bufi][1][(wid * 64 + i * 256) * 8];
      __builtin_amdgcn_global_load_lds(
          (__attribute__((address_space(1))) void*)ga,
          (__attribute__((address_space(3))) void*)la, 16, 0, 0);
    }
  };

  f4v acc[4][4] = {};

  stage(0, 0);
  __syncthreads();
  int buf = 0;
  const int nk = K / 32;
  for (int kt = 0; kt < nk; ++kt) {
    if (kt + 1 < nk) stage(buf ^ 1, kt + 1);
    s8v af[4], bfv[4];
#pragma unroll
    for (int m = 0; m < 4; ++m) {
      int row = wr * 64 + m * 16 + (lane & 15);
      int slot = (lane >> 4) ^ ((row >> 1) & 3);
      af[m] = *(const s8v*)&lds[buf][0][row * 32 + slot * 8];
    }
#pragma unroll
    for (int n = 0; n < 4; ++n) {
      int row = wc * 64 + n * 16 + (lane & 15);
      int slot = (lane >> 4) ^ ((row >> 1) & 3);
      bfv[n] = *(const s8v*)&lds[buf][1][row * 32 + slot * 8];
    }
#pragma unroll
    for (int m = 0; m < 4; ++m)
#pragma unroll
      for (int n = 0; n < 4; ++n)
        acc[m][n] = __builtin_amdgcn_mfma_f32_16x16x32_bf16(af[m], bfv[n], acc[m][n], 0, 0, 0);
    __syncthreads();
    buf ^= 1;
  }

#pragma unroll
  for (int m = 0; m < 4; ++m)
#pragma unroll
    for (int n = 0; n < 4; ++n)
#pragma unroll
      for (int j = 0; j < 4; ++j) {
        int row = tm * 128 + wr * 64 + m * 16 + (lane >> 4) * 4 + j;  // C: row=(l>>4)*4+j
        int col = tn * 128 + wc * 64 + n * 16 + (lane & 15);          //    col=l&15 (m89)
        float v = acc[m][n][j];
        if (MODE == 0) {
          if (row < M_) {
            float val = v + bias[col];
            int which = col / 768, rem = col % 768;
            int h = rem >> 6, d = rem & 63;
            int bb = row / S_, s = row % S_;
            ((bf16*)dst)[((size_t)((which * B_ + bb) * H_ + h) * S_ + s) * 64 + d] =
                __float2bfloat16(val);
          }
        } else if (MODE == 1) {
          if (row < M_) {
            float val = v + bias[col] + resid[(size_t)row * N + col];
            ((float*)dst)[(size_t)row * N + col] = val;
          }
        } else {
          float val = v + bias[col];
          val = 0.5f * val * (1.f + erff(val * 0.70710678f));
          ((bf16*)dst)[(size_t)row * N + col] = __float2bfloat16(val);
        }
      }
}

// ---------------- cls-token attention: block per (b,h), softmax over S keys ----------------
__global__ __launch_bounds__(256)
void cls_attn(const bf16* __restrict__ QKVb, bf16* __restrict__ out) {
  int b = blockIdx.x / H_, h = blockIdx.x % H_;
  const bf16* q  = QKVb + ((size_t)((0 * B_ + b) * H_ + h) * S_) * 64;
  const bf16* Kr = QKVb + ((size_t)((1 * B_ + b) * H_ + h) * S_) * 64;
  const bf16* Vr = QKVb + ((size_t)((2 * B_ + b) * H_ + h) * S_) * 64;
  __shared__ float qf[64];
  __shared__ float sc[S_];
  __shared__ float redm[4], reds[4];
  __shared__ float pv[4][64];
  int t = threadIdx.x;
  if (t < 64) qf[t] = __bfloat162float(q[t]);
  __syncthreads();
  for (int k = t; k < S_; k += 256) {
    const bf16* kr = Kr + (size_t)k * 64;
    float s = 0.f;
#pragma unroll
    for (int d = 0; d < 64; ++d) s += qf[d] * __bfloat162float(kr[d]);
    sc[k] = s * 0.125f;
  }
  __syncthreads();
  float mx = -1e30f;
  for (int k = t; k < S_; k += 256) mx = fmaxf(mx, sc[k]);
#pragma unroll
  for (int o = 32; o; o >>= 1) mx = fmaxf(mx, __shfl_xor(mx, o));
  if ((t & 63) == 0) redm[t >> 6] = mx;
  __syncthreads();
  mx = fmaxf(fmaxf(redm[0], redm[1]), fmaxf(redm[2], redm[3]));
  float sum = 0.f;
  for (int k = t; k < S_; k += 256) { float e = __expf(sc[k] - mx); sc[k] = e; sum += e; }
#pragma unroll
  for (int o = 32; o; o >>= 1) sum += __shfl_xor(sum, o);
  if ((t & 63) == 0) reds[t >> 6] = sum;
  __syncthreads();
  sum = reds[0] + reds[1] + reds[2] + reds[3];
  float inv = 1.f / sum;
  int d = t & 63, kg = t >> 6;
  float acc = 0.f;
  for (int k = kg; k < S_; k += 4) acc += sc[k] * __bfloat162float(Vr[(size_t)k * 64 + d]);
  pv[kg][d] = acc;
  __syncthreads();
  if (t < 64) {
    float ov = (pv[0][t] + pv[1][t] + pv[2][t] + pv[3][t]) * inv;
    out[(size_t)(b * S_) * D_ + h * 64 + t] = __float2bfloat16(ov);
  }
}

// ---------------- routed attention: thread per (b,h,p), 32 gathered keys ----------------
__global__ __launch_bounds__(256)
void routed_attn(const bf16* __restrict__ QKVb, const int* __restrict__ routes,
                 bf16* __restrict__ out) {
  int tid = blockIdx.x * 256 + threadIdx.x;  // B*H*P = 49152
  int h = tid % H_;
  int bp = tid / H_;
  int p = bp % P_, b = bp / P_;
  const bf16* Qp    = QKVb + ((size_t)((0 * B_ + b) * H_ + h) * S_ + (p + 1)) * 64;
  const bf16* Kbase = QKVb + ((size_t)((1 * B_ + b) * H_ + h) * S_) * 64;
  const bf16* Vbase = QKVb + ((size_t)((2 * B_ + b) * H_ + h) * S_) * 64;
  const uint4* q4 = (const uint4*)Qp;
  uint4 qv[8];
#pragma unroll
  for (int i = 0; i < 8; ++i) qv[i] = q4[i];
  const int* rt = routes + (size_t)p * KNB;
  int ridx[KNB];
#pragma unroll
  for (int k = 0; k < KNB; ++k) ridx[k] = rt[k] + 1;
  float sc[KNB];
  float mx = -1e30f;
#pragma unroll
  for (int k = 0; k < KNB; ++k) {
    const uint4* k4 = (const uint4*)(Kbase + (size_t)ridx[k] * 64);
    float s = 0.f;
#pragma unroll
    for (int i = 0; i < 8; ++i) {
      uint4 kv = k4[i];
      s += b2f_lo(kv.x) * b2f_lo(qv[i].x) + b2f_hi(kv.x) * b2f_hi(qv[i].x);
      s += b2f_lo(kv.y) * b2f_lo(qv[i].y) + b2f_hi(kv.y) * b2f_hi(qv[i].y);
      s += b2f_lo(kv.z) * b2f_lo(qv[i].z) + b2f_hi(kv.z) * b2f_hi(qv[i].z);
      s += b2f_lo(kv.w) * b2f_lo(qv[i].w) + b2f_hi(kv.w) * b2f_hi(qv[i].w);
    }
    sc[k] = s * 0.125f;
    mx = fmaxf(mx, sc[k]);
  }
  float sum = 0.f;
#pragma unroll
  for (int k = 0; k < KNB; ++k) { sc[k] = __expf(sc[k] - mx); sum += sc[k]; }
  float inv = 1.f / sum;
  float acc[64];
#pragma unroll
  for (int d = 0; d < 64; ++d) acc[d] = 0.f;
#pragma unroll
  for (int k = 0; k < KNB; ++k) {
    const uint4* v4 = (const uint4*)(Vbase + (size_t)ridx[k] * 64);
    float w = sc[k] * inv;
#pragma unroll
    for (int i = 0; i < 8; ++i) {
      uint4 vv = v4[i];
      acc[i * 8 + 0] += w * b2f_lo(vv.x); acc[i * 8 + 1] += w * b2f_hi(vv.x);
      acc[i * 8 + 2] += w * b2f_lo(vv.y); acc[i * 8 + 3] += w * b2f_hi(vv.y);
      acc[i * 8 + 4] += w * b2f_lo(vv.z); acc[i * 8 + 5] += w * b2f_hi(vv.z);
      acc[i * 8 + 6] += w * b2f_lo(vv.w); acc[i * 8 + 7] += w * b2f_hi(vv.w);
    }
  }
  bf16* o = out + (size_t)(b * S_ + p + 1) * D_ + h * 64;
#pragma unroll
  for (int d = 0; d < 64; ++d) o[d] = __float2bfloat16(acc[d]);
}

extern "C" void kernel_launch(void* const* d_in, const int* in_sizes, int n_in,
                              void* d_out, int out_size, void* d_ws, size_t ws_size,
                              hipStream_t stream) {
  const float* x      = (const float*)d_in[0];
  const int*   routes = (const int*)d_in[1];
  const float* qkv_w  = (const float*)d_in[2];
  const float* qkv_b  = (const float*)d_in[3];
  const float* proj_w = (const float*)d_in[4];
  const float* proj_b = (const float*)d_in[5];
  const float* ln1_w  = (const float*)d_in[6];
  const float* ln1_b  = (const float*)d_in[7];
  const float* ln2_w  = (const float*)d_in[8];
  const float* ln2_b  = (const float*)d_in[9];
  const float* mlp_w1 = (const float*)d_in[10];
  const float* mlp_b1 = (const float*)d_in[11];
  const float* mlp_w2 = (const float*)d_in[12];
  const float* mlp_b2 = (const float*)d_in[13];
  float* out = (float*)d_out;

  // workspace layout (~52.5 MB)
  bf16* qkvw_t  = (bf16*)d_ws;                       // [2304][768]
  bf16* projw_t = qkvw_t + 2304 * 768;               // [768][768]
  bf16* mlpw1_t = projw_t + 768 * 768;               // [3072][768]
  bf16* mlpw2_t = mlpw1_t + 3072 * 768;              // [768][3072]
  bf16* xnA     = mlpw2_t + 768 * 3072;              // [4224][768]
  bf16* qkvbuf  = xnA + (size_t)MPAD * 768;          // [3][B][H][S][64]
  bf16* attn    = qkvbuf + (size_t)3 * B_ * H_ * S_ * 64;  // [4224][768]
  bf16* h2      = attn + (size_t)MPAD * 768;         // [4224][768]
  bf16* g       = xnA;  // alias over [xnA..attn end): needs 4224*3072, have 15.9M elems

  wt_conv<768, 2304><<<dim3(24, 72), 256, 0, stream>>>(qkv_w, qkvw_t);
  wt_conv<768, 768><<<dim3(24, 24), 256, 0, stream>>>(proj_w, projw_t);
  wt_conv<768, 3072><<<dim3(24, 96), 256, 0, stream>>>(mlp_w1, mlpw1_t);
  wt_conv<3072, 768><<<dim3(96, 24), 256, 0, stream>>>(mlp_w2, mlpw2_t);

  ln_kernel<<<M_, 256, 0, stream>>>(x, ln1_w, ln1_b, xnA);

  gemm_bf16<2304, 768, 0><<<dim3(33, 18), 256, 0, stream>>>(xnA, qkvw_t, qkv_b, nullptr, qkvbuf);

  cls_attn<<<B_ * H_, 256, 0, stream>>>(qkvbuf, attn);
  routed_attn<<<192, 256, 0, stream>>>(qkvbuf, routes, attn);

  gemm_bf16<768, 768, 1><<<dim3(33, 6), 256, 0, stream>>>(attn, projw_t, proj_b, x, out);

  ln_kernel<<<M_, 256, 0, stream>>>(out, ln2_w, ln2_b, h2);

  gemm_bf16<3072, 768, 2><<<dim3(33, 24), 256, 0, stream>>>(h2, mlpw1_t, mlp_b1, nullptr, g);

  gemm_bf16<768, 3072, 1><<<dim3(33, 6), 256, 0, stream>>>(g, mlpw2_t, mlp_b2, out, out);
}